// Round 20
// baseline (229.713 us; speedup 1.0000x reference)
//
#include <hip/hip_runtime.h>
#include <hip/hip_bf16.h>

// ViT encoder block: B=8, N=1024, C=768, H=12, DH=64, FF=3072, fp32 in/out,
// bf16 MFMA compute internally.
#define BDIM 8
#define SEQ  1024
#define CH   768
#define NHD  12
#define DHD  64
#define FFD  3072
#define MR   (BDIM*SEQ)   // 8192 token rows

typedef __attribute__((ext_vector_type(8))) short bf16x8;
typedef __attribute__((ext_vector_type(4))) float f32x4;
typedef unsigned int   u32;
typedef unsigned short u16;

#define QSCL 0.18033688f   // 0.125 * log2(e): Q pre-scale -> scores in log2

__device__ __forceinline__ u16 f2bfu(float x) {
  __hip_bfloat16 h = __float2bfloat16(x);
  return *reinterpret_cast<u16*>(&h);
}

__device__ __forceinline__ float bfu2f(u16 v) {
  u32 u = (u32)v << 16;
  return __uint_as_float(u);
}

__device__ __forceinline__ void glds16(const void* g, void* l) {
  __builtin_amdgcn_global_load_lds(
      (const __attribute__((address_space(1))) u32*)g,
      (__attribute__((address_space(3))) u32*)l, 16, 0, 0);
}

// ---------------------------------------------------------------- prelude
// ONE launch fusing three independent jobs:
//   blocks [0,6912):         weight transposes fp32 -> bf16 [N][K]
//   blocks [6912,6921):      bias pack bq|bk|bv -> bdst
//   blocks [6921,6921+2048): LN1  x -> xn (bf16)
__global__ __launch_bounds__(256) void k_prelude(
    const float* __restrict__ Wq, const float* __restrict__ Wk,
    const float* __restrict__ Wv, const float* __restrict__ Wo,
    const float* __restrict__ W1, const float* __restrict__ W2,
    u16* __restrict__ ws, const float* __restrict__ bq,
    const float* __restrict__ bk, const float* __restrict__ bv,
    float* __restrict__ bdst, const float* __restrict__ x,
    const float* __restrict__ g1, const float* __restrict__ b1,
    u16* __restrict__ xn) {
  __shared__ float tile[32][33];
  int b = blockIdx.x;
  if (b >= 6921) {
    // ---- LN1 (fp32 source) ----
    int row  = (b - 6921) * 4 + (threadIdx.x >> 6);
    int lane = threadIdx.x & 63;
    const float4* p4 = (const float4*)(x + (size_t)row * CH);
    float4 v[3];
    float s = 0.f, s2 = 0.f;
#pragma unroll
    for (int k = 0; k < 3; k++) {
      v[k] = p4[lane + k * 64];
      s  += v[k].x + v[k].y + v[k].z + v[k].w;
      s2 += v[k].x * v[k].x + v[k].y * v[k].y + v[k].z * v[k].z +
            v[k].w * v[k].w;
    }
#pragma unroll
    for (int m = 1; m < 64; m <<= 1) {
      s  += __shfl_xor(s,  m, 64);
      s2 += __shfl_xor(s2, m, 64);
    }
    float mean = s * (1.f / CH);
    float var  = s2 * (1.f / CH) - mean * mean;
    float rs   = rsqrtf(var + 1e-5f);
    u16* drow = xn + (size_t)row * CH;
#pragma unroll
    for (int k = 0; k < 3; k++) {
      int col = lane * 4 + k * 256;
      float4 gq = ((const float4*)g1)[lane + k * 64];
      float4 bq2 = ((const float4*)b1)[lane + k * 64];
      u32 lo = (u32)f2bfu((v[k].x - mean) * rs * gq.x + bq2.x) |
               ((u32)f2bfu((v[k].y - mean) * rs * gq.y + bq2.y) << 16);
      u32 hi = (u32)f2bfu((v[k].z - mean) * rs * gq.z + bq2.z) |
               ((u32)f2bfu((v[k].w - mean) * rs * gq.w + bq2.w) << 16);
      uint2 w; w.x = lo; w.y = hi;
      *(uint2*)(drow + col) = w;
    }
    return;
  }
  if (b >= 6912) {
    int i = (b - 6912) * 256 + threadIdx.x;
    if (i < 3 * CH)
      bdst[i] = i < CH ? bq[i] : (i < 2 * CH ? bk[i - CH] : bv[i - 2 * CH]);
    return;
  }
  int id, tb;
  if (b < 2304)      { id = b / 576; tb = b % 576; }
  else if (b < 4608) { id = 4;       tb = b - 2304; }
  else               { id = 5;       tb = b - 4608; }
  const float* src;
  u16* dst;
  int K, Nc;
  switch (id) {
    case 0: src = Wq; dst = ws;                      K = CH;  Nc = CH;  break;
    case 1: src = Wk; dst = ws + (size_t)CH*CH;      K = CH;  Nc = CH;  break;
    case 2: src = Wv; dst = ws + (size_t)2*CH*CH;    K = CH;  Nc = CH;  break;
    case 3: src = Wo; dst = ws + (size_t)3*CH*CH;    K = CH;  Nc = CH;  break;
    case 4: src = W1; dst = ws + (size_t)4*CH*CH;    K = CH;  Nc = FFD; break;
    default:src = W2; dst = ws + (size_t)4*CH*CH + (size_t)CH*FFD;
                                                     K = FFD; Nc = CH;  break;
  }
  int tilesx = Nc >> 5;
  int bx = (tb % tilesx) * 32;        // Nc dim
  int by = (tb / tilesx) * 32;        // K dim
  int tx = threadIdx.x & 31, ty = threadIdx.x >> 5;   // 32 x 8
#pragma unroll
  for (int j = 0; j < 32; j += 8)
    tile[ty + j][tx] = src[(size_t)(by + ty + j) * Nc + bx + tx];
  __syncthreads();
#pragma unroll
  for (int j = 0; j < 32; j += 8)
    dst[(size_t)(bx + ty + j) * K + by + tx] = f2bfu(tile[tx][ty + j]);
}

// ---------------------------------------------------------------- layernorm
// bf16 source (LN2: reads bres trunk stored bf16 -- halves its HBM fetch)
__global__ __launch_bounds__(256) void k_layernorm_b16src(
    const u16* __restrict__ src, const float* __restrict__ gamma,
    const float* __restrict__ beta, u16* __restrict__ dst) {
  int row  = blockIdx.x * 4 + (threadIdx.x >> 6);
  int lane = threadIdx.x & 63;
  const uint2* p2 = (const uint2*)(src + (size_t)row * CH);
  float v[3][4];
  float s = 0.f, s2 = 0.f;
#pragma unroll
  for (int k = 0; k < 3; k++) {
    uint2 w = p2[lane + k * 64];
    v[k][0] = bfu2f((u16)(w.x & 0xFFFF));
    v[k][1] = bfu2f((u16)(w.x >> 16));
    v[k][2] = bfu2f((u16)(w.y & 0xFFFF));
    v[k][3] = bfu2f((u16)(w.y >> 16));
#pragma unroll
    for (int j = 0; j < 4; j++) { s += v[k][j]; s2 += v[k][j] * v[k][j]; }
  }
#pragma unroll
  for (int m = 1; m < 64; m <<= 1) {
    s  += __shfl_xor(s,  m, 64);
    s2 += __shfl_xor(s2, m, 64);
  }
  float mean = s * (1.f / CH);
  float var  = s2 * (1.f / CH) - mean * mean;
  float rs   = rsqrtf(var + 1e-5f);
  u16* drow = dst + (size_t)row * CH;
#pragma unroll
  for (int k = 0; k < 3; k++) {
    int col = lane * 4 + k * 256;
    float4 gq = ((const float4*)gamma)[lane + k * 64];
    float4 bq = ((const float4*)beta )[lane + k * 64];
    u32 lo = (u32)f2bfu((v[k][0] - mean) * rs * gq.x + bq.x) |
             ((u32)f2bfu((v[k][1] - mean) * rs * gq.y + bq.y) << 16);
    u32 hi = (u32)f2bfu((v[k][2] - mean) * rs * gq.z + bq.z) |
             ((u32)f2bfu((v[k][3] - mean) * rs * gq.w + bq.w) << 16);
    uint2 w; w.x = lo; w.y = hi;
    *(uint2*)(drow + col) = w;
  }
}

enum { EPI_QKV = 0, EPI_BRES = 1, EPI_RELU = 2, EPI_OUT = 3 };

// ------------------------------------------------- shared epilogue (16x16)
// D row = (lane>>4)*4 + r, col = lane&15 (m89-verified mapping). row0 % 4 == 0.
// EPI_QKV: Q (sel==0) PRE-SCALED by QSCL (scores arrive in log2 domain).
// EPI_BRES: Wo out -- b = val + x(fp32), stored bf16 (trunk).
// EPI_OUT:  W2 out -- y = val + b(bf16), stored fp32 (final output).
template <int EPI>
__device__ __forceinline__ void gemm_epi(const f32x4& a, int row0, int col,
                                         float bval, const void* resid,
                                         void* outp, int Nmat) {
  if constexpr (EPI == EPI_QKV) {
    int sel = col / CH;                       // 128-col tile is within one sel
    int c = col - sel * CH;
    int h = c >> 6, d = c & 63;
    int bb = row0 >> 10, nn0 = row0 & (SEQ - 1);
    if (sel == 2) {
      // V stored TRANSPOSED per head: [B*H][DH][N]; 4 consecutive token rows
      union { uint2 u; u16 h4[4]; } pk;
#pragma unroll
      for (int r = 0; r < 4; r++) pk.h4[r] = f2bfu(a[r] + bval);
      *(uint2*)&((u16*)outp)[(size_t)2 * MR * CH +
                             (((size_t)(bb * NHD + h)) * DHD + d) * SEQ + nn0] =
          pk.u;
    } else {
      float scl = (sel == 0) ? QSCL : 1.f;    // uniform per col-tile
#pragma unroll
      for (int r = 0; r < 4; r++)
        ((u16*)outp)[(size_t)sel * MR * CH +
                     (((size_t)(bb * NHD + h)) * SEQ + nn0 + r) * DHD + d] =
            f2bfu((a[r] + bval) * scl);
    }
  } else if constexpr (EPI == EPI_BRES) {
#pragma unroll
    for (int r = 0; r < 4; r++) {
      size_t idx = (size_t)(row0 + r) * Nmat + col;
      ((u16*)outp)[idx] = f2bfu(a[r] + bval + ((const float*)resid)[idx]);
    }
  } else if constexpr (EPI == EPI_OUT) {
#pragma unroll
    for (int r = 0; r < 4; r++) {
      size_t idx = (size_t)(row0 + r) * Nmat + col;
      ((float*)outp)[idx] = a[r] + bval + bfu2f(((const u16*)resid)[idx]);
    }
  } else {  // RELU -> bf16 row-major
#pragma unroll
    for (int r = 0; r < 4; r++) {
      float val = a[r] + bval;
      ((u16*)outp)[(size_t)(row0 + r) * Nmat + col] =
          f2bfu(val > 0.f ? val : 0.f);
    }
  }
}

// ---------------------------------------------------------------- GEMM BK64
// Round-11/12 proven 2-phase: TM=64, BN=128, BK=64, conflicts 0 via row&7
// XOR swizzle (pre-swizzled source, dest linear, rule #21). LDS 48KB ->
// 3 blk/CU. Natural dispatch. QKV, Wo, W2 (grids 2304 / 768 / 768 blocks).
template <int EPI>
__global__ __launch_bounds__(256, 2) void k_gemmk64(
    const u16* __restrict__ A, const u16* __restrict__ Bt,
    const float* __restrict__ bias, const void* __restrict__ resid,
    void* __restrict__ outp, int K, int Nmat) {
  __shared__ u16 As[2][64 * 64];
  __shared__ u16 Bs[2][128 * 64];
  int tid = threadIdx.x;
  int bm = blockIdx.x, bn = blockIdx.y;
  int lane = tid & 63, wid = tid >> 6;
  int wr = (wid >> 1) * 32, wc = (wid & 1) * 64;
  int lrow = lane & 15, g = lane >> 4;

  const u16* Abase = A + (size_t)(bm * 64) * K;
  const u16* Bbase = Bt + (size_t)(bn * 128) * K;

  auto stage = [&](int buf, int k0) {
#pragma unroll
    for (int r = 0; r < 2; r++) {               // A: 512 units
      int u = tid + r * 256;
      int row = u >> 3, slot = u & 7;
      glds16(Abase + (size_t)row * K + k0 + ((slot ^ (row & 7)) << 3),
             &As[buf][u * 8]);
    }
#pragma unroll
    for (int r = 0; r < 4; r++) {               // B: 1024 units
      int u = tid + r * 256;
      int row = u >> 3, slot = u & 7;
      glds16(Bbase + (size_t)row * K + k0 + ((slot ^ (row & 7)) << 3),
             &Bs[buf][u * 8]);
    }
  };

  int sx = lrow & 7;
  int x0 = (g ^ sx) * 8;            // ks=0: logical slot g
  int x1 = ((4 + g) ^ sx) * 8;      // ks=1: logical slot 4+g

  f32x4 acc[2][4];
#pragma unroll
  for (int m = 0; m < 2; m++)
#pragma unroll
    for (int n = 0; n < 4; n++) acc[m][n] = {0.f, 0.f, 0.f, 0.f};

  int nk = K >> 6;
  stage(0, 0);
  for (int kt = 0; kt < nk; ++kt) {
    int buf = kt & 1;
    __syncthreads();
    if (kt + 1 < nk) stage(buf ^ 1, (kt + 1) << 6);
#pragma unroll
    for (int ks = 0; ks < 2; ks++) {
      int xs = ks ? x1 : x0;
      bf16x8 af[2], bfr[4];
#pragma unroll
      for (int m = 0; m < 2; m++)
        af[m] = *(const bf16x8*)&As[buf][(wr + m * 16 + lrow) * 64 + xs];
#pragma unroll
      for (int n = 0; n < 4; n++)
        bfr[n] = *(const bf16x8*)&Bs[buf][(wc + n * 16 + lrow) * 64 + xs];
      __builtin_amdgcn_s_setprio(1);
#pragma unroll
      for (int m = 0; m < 2; m++)
#pragma unroll
        for (int n = 0; n < 4; n++)
          acc[m][n] = __builtin_amdgcn_mfma_f32_16x16x32_bf16(
              af[m], bfr[n], acc[m][n], 0, 0, 0);
      __builtin_amdgcn_s_setprio(0);
    }
  }

#pragma unroll
  for (int m = 0; m < 2; m++) {
    int row0 = bm * 64 + wr + m * 16 + g * 4;
#pragma unroll
    for (int n = 0; n < 4; n++) {
      int col = bn * 128 + wc + n * 16 + lrow;
      gemm_epi<EPI>(acc[m][n], row0, col, bias[col], resid, outp, Nmat);
    }
  }
}

// ---------------------------------------------------------------- GEMM 128x64
// TM=128, BN=128, BK=64: 2x MFMA per barrier at MFMA:ds ratio 2.0. LDS 64KB
// -> 2 blk/CU. Round-16: wins for W1 (grid 1536 = 3 full dispatch rounds,
// 48 K-tiles); loses for QKV (tail). W1 ONLY.
template <int EPI>
__global__ __launch_bounds__(256, 2) void k_gemm128(
    const u16* __restrict__ A, const u16* __restrict__ Bt,
    const float* __restrict__ bias, const void* __restrict__ resid,
    void* __restrict__ outp, int K, int Nmat) {
  __shared__ u16 As[2][128 * 64];
  __shared__ u16 Bs[2][128 * 64];
  int tid = threadIdx.x;
  int bm = blockIdx.x, bn = blockIdx.y;
  int lane = tid & 63, wid = tid >> 6;
  int wr = (wid >> 1) * 64, wc = (wid & 1) * 64;
  int lrow = lane & 15, g = lane >> 4;

  const u16* Abase = A + (size_t)(bm * 128) * K;
  const u16* Bbase = Bt + (size_t)(bn * 128) * K;

  auto stage = [&](int buf, int k0) {
#pragma unroll
    for (int r = 0; r < 4; r++) {               // A: 1024 units
      int u = tid + r * 256;
      int row = u >> 3, slot = u & 7;
      glds16(Abase + (size_t)row * K + k0 + ((slot ^ (row & 7)) << 3),
             &As[buf][u * 8]);
    }
#pragma unroll
    for (int r = 0; r < 4; r++) {               // B: 1024 units
      int u = tid + r * 256;
      int row = u >> 3, slot = u & 7;
      glds16(Bbase + (size_t)row * K + k0 + ((slot ^ (row & 7)) << 3),
             &Bs[buf][u * 8]);
    }
  };

  int sx = lrow & 7;
  int x0 = (g ^ sx) * 8;            // ks=0: logical slot g
  int x1 = ((4 + g) ^ sx) * 8;      // ks=1: logical slot 4+g

  f32x4 acc[4][4];
#pragma unroll
  for (int m = 0; m < 4; m++)
#pragma unroll
    for (int n = 0; n < 4; n++) acc[m][n] = {0.f, 0.f, 0.f, 0.f};

  int nk = K >> 6;
  stage(0, 0);
  for (int kt = 0; kt < nk; ++kt) {
    int buf = kt & 1;
    __syncthreads();
    if (kt + 1 < nk) stage(buf ^ 1, (kt + 1) << 6);
#pragma unroll
    for (int ks = 0; ks < 2; ks++) {
      int xs = ks ? x1 : x0;
      bf16x8 af[4], bfr[4];
#pragma unroll
      for (int m = 0; m < 4; m++)
        af[m] = *(const bf16x8*)&As[buf][(wr + m * 16 + lrow) * 64 + xs];
#pragma unroll
      for (int n = 0; n < 4; n++)
        bfr[n] = *(const bf16x8*)&Bs[buf][(wc + n * 16 + lrow) * 64 + xs];
      __builtin_amdgcn_s_setprio(1);
#pragma unroll
      for (int m = 0; m < 4; m++)
#pragma unroll
        for (int n = 0; n < 4; n++)
          acc[m][n] = __builtin_amdgcn_mfma_f32_16x16x32_bf16(
              af[m], bfr[n], acc[m][n], 0, 0, 0);
      __builtin_amdgcn_s_setprio(0);
    }
  }

#pragma unroll
  for (int m = 0; m < 4; m++) {
    int row0 = bm * 128 + wr + m * 16 + g * 4;
#pragma unroll
    for (int n = 0; n < 4; n++) {
      int col = bn * 128 + wc + n * 16 + lrow;
      gemm_epi<EPI>(acc[m][n], row0, col, bias[col], resid, outp, Nmat);
    }
  }
}

// ---------------------------------------------------------------- attention
// flash-style, SWAPPED QK^T, glds-staged swizzled K / V^T tiles, defer-max,
// 8 waves x 16 q-rows, XCD swizzle, Q pre-scaled to log2 domain, raw
// v_exp_f32, MFMA row-sum denominator, max3 tree. Round-20: P repack via
// IN-REGISTER __shfl (8 shfl + 4 sel per ks-half) instead of the 18KB Psu
// LDS table -> LDS 51.2 -> 32.75KB -> 4 blocks/CU (32-wave cap), +33%
// occupancy for this latency-bound kernel. Same provider/index derivation
// (laneA = lrow+((g&1)<<5), laneB = laneA+16, nks = 2ks+(g>>1)).
__global__ __launch_bounds__(512, 4) void k_attn(
    const u16* __restrict__ Q, const u16* __restrict__ Kk,
    const u16* __restrict__ Vt, u16* __restrict__ Z) {
  __shared__ u16 Ks[2][64 * 64];
  __shared__ u16 Vs[2][64 * 64];     // V^T tile: [d][kv]
  int tid = threadIdx.x, lane = tid & 63;
  int lrow = lane & 15, g = lane >> 4;
  int id  = blockIdx.x;
  int nid = (id & 7) * 96 + (id >> 3);
  int bh = nid >> 3;
  int qtile = (nid & 7) * 128;
  size_t base = (size_t)bh * SEQ * DHD;
  int bb = bh / NHD, hh = bh % NHD;
  int qrow0 = qtile + (tid >> 6) * 16;

  bf16x8 qf[2];
#pragma unroll
  for (int ks = 0; ks < 2; ks++)
    qf[ks] = *(const bf16x8*)(Q + base + (size_t)(qrow0 + lrow) * DHD +
                              ks * 32 + g * 8);

  bf16x8 vone;
#pragma unroll
  for (int j = 0; j < 8; j++) vone[j] = (short)0x3F80;   // bf16 1.0

  f32x4 accO[4];
  f32x4 accS = {0.f, 0.f, 0.f, 0.f};   // denominator, same layout as accO
  float mrun = -1e30f;                  // log2 units
#pragma unroll
  for (int n = 0; n < 4; n++) accO[n] = {0.f, 0.f, 0.f, 0.f};

  int srow = tid >> 3;
  int swz  = (((tid & 7) * 16) ^ ((srow & 7) << 4)) >> 1;   // u16 units
  const u16* kg0 = Kk + base + (size_t)srow * DHD + swz;
  const u16* vg0 = Vt + base + (size_t)srow * SEQ + swz;

  auto stageKV = [&](int buf, int t) {
    glds16(kg0 + (size_t)t * 64 * DHD, &Ks[buf][tid * 8]);
    glds16(vg0 + t * 64,               &Vs[buf][tid * 8]);
  };

  int rc0 = ((g * 16)      ^ ((lrow & 7) << 4)) >> 1;
  int rc1 = ((64 + g * 16) ^ ((lrow & 7) << 4)) >> 1;

  auto mx3 = [](float a, float b, float c) { return fmaxf(fmaxf(a, b), c); };

  int laneA = lrow + ((g & 1) << 5);
  int laneB = laneA + 16;
  int nsel = g >> 1;

  stageKV(0, 0);
  for (int t = 0; t < 16; ++t) {
    int buf = t & 1;
    __syncthreads();
    if (t + 1 < 16) stageKV(buf ^ 1, t + 1);

    f32x4 sacc[4];
    __builtin_amdgcn_s_setprio(1);
#pragma unroll
    for (int n = 0; n < 4; n++) {
      bf16x8 kf0 = *(const bf16x8*)&Ks[buf][(n * 16 + lrow) * 64 + rc0];
      bf16x8 kf1 = *(const bf16x8*)&Ks[buf][(n * 16 + lrow) * 64 + rc1];
      sacc[n] = {0.f, 0.f, 0.f, 0.f};
      sacc[n] = __builtin_amdgcn_mfma_f32_16x16x32_bf16(kf0, qf[0], sacc[n], 0, 0, 0);
      sacc[n] = __builtin_amdgcn_mfma_f32_16x16x32_bf16(kf1, qf[1], sacc[n], 0, 0, 0);
    }
    __builtin_amdgcn_s_setprio(0);

    float a0 = mx3(sacc[0][0], sacc[0][1], sacc[0][2]);
    float a1 = mx3(sacc[0][3], sacc[1][0], sacc[1][1]);
    float a2 = mx3(sacc[1][2], sacc[1][3], sacc[2][0]);
    float a3 = mx3(sacc[2][1], sacc[2][2], sacc[2][3]);
    float a4 = mx3(sacc[3][0], sacc[3][1], sacc[3][2]);
    float mx = fmaxf(mx3(a0, a1, a2), mx3(a3, a4, sacc[3][3]));
    mx = fmaxf(mx, __shfl_xor(mx, 16, 64));
    mx = fmaxf(mx, __shfl_xor(mx, 32, 64));

    if (__all(mx <= mrun + 11.54f)) {   // 8 nats in bits
#pragma unroll
      for (int n = 0; n < 4; n++)
#pragma unroll
        for (int r = 0; r < 4; r++)
          sacc[n][r] = __builtin_amdgcn_exp2f(sacc[n][r] - mrun);
    } else {
      float mnew = fmaxf(mrun, mx);
      float alpha = __builtin_amdgcn_exp2f(mrun - mnew);
#pragma unroll
      for (int n = 0; n < 4; n++)
#pragma unroll
        for (int r = 0; r < 4; r++)
          sacc[n][r] = __builtin_amdgcn_exp2f(sacc[n][r] - mnew);
      mrun = mnew;
#pragma unroll
      for (int r = 0; r < 4; r++) {
        float ar = __shfl(alpha, (lane & 48) | (g * 4 + r), 64);
        accS[r] *= ar;
#pragma unroll
        for (int n = 0; n < 4; n++) accO[n][r] *= ar;
      }
    }

    // pack P to bf16 pairs -- REGISTERS only (compile-time indices)
    u32 lo[4], hi[4];
#pragma unroll
    for (int n = 0; n < 4; n++) {
      lo[n] = (u32)f2bfu(sacc[n][0]) | ((u32)f2bfu(sacc[n][1]) << 16);
      hi[n] = (u32)f2bfu(sacc[n][2]) | ((u32)f2bfu(sacc[n][3]) << 16);
    }

    __builtin_amdgcn_s_setprio(1);
#pragma unroll
    for (int ks = 0; ks < 2; ks++) {
      // gather laneA/laneB's (lo,hi) at index nks = 2ks + nsel via shfl+sel
      u32 qa0 = (u32)__shfl((int)lo[2 * ks],     laneA, 64);
      u32 qa1 = (u32)__shfl((int)lo[2 * ks + 1], laneA, 64);
      u32 qb0 = (u32)__shfl((int)hi[2 * ks],     laneA, 64);
      u32 qb1 = (u32)__shfl((int)hi[2 * ks + 1], laneA, 64);
      u32 qc0 = (u32)__shfl((int)lo[2 * ks],     laneB, 64);
      u32 qc1 = (u32)__shfl((int)lo[2 * ks + 1], laneB, 64);
      u32 qd0 = (u32)__shfl((int)hi[2 * ks],     laneB, 64);
      u32 qd1 = (u32)__shfl((int)hi[2 * ks + 1], laneB, 64);
      union { bf16x8 v; u32 w[4]; } pk;
      pk.w[0] = nsel ? qa1 : qa0;
      pk.w[1] = nsel ? qb1 : qb0;
      pk.w[2] = nsel ? qc1 : qc0;
      pk.w[3] = nsel ? qd1 : qd0;
      int rc = ks ? rc1 : rc0;
#pragma unroll
      for (int n = 0; n < 4; n++) {
        bf16x8 vf = *(const bf16x8*)&Vs[buf][(n * 16 + lrow) * 64 + rc];
        accO[n] = __builtin_amdgcn_mfma_f32_16x16x32_bf16(pk.v, vf,
                                                          accO[n], 0, 0, 0);
      }
      accS = __builtin_amdgcn_mfma_f32_16x16x32_bf16(pk.v, vone, accS, 0, 0, 0);
    }
    __builtin_amdgcn_s_setprio(0);
  }

#pragma unroll
  for (int r = 0; r < 4; r++) {
    float inv = 1.f / accS[r];
    int qrow = qrow0 + g * 4 + r;
#pragma unroll
    for (int n = 0; n < 4; n++) {
      int d = n * 16 + lrow;
      Z[((size_t)(bb * SEQ + qrow)) * CH + hh * DHD + d] =
          f2bfu(accO[n][r] * inv);
    }
  }
}

// ---------------------------------------------------------------- launch
extern "C" void kernel_launch(void* const* d_in, const int* in_sizes, int n_in,
                              void* d_out, int out_size, void* d_ws,
                              size_t ws_size, hipStream_t stream) {
  (void)in_sizes; (void)n_in; (void)out_size; (void)ws_size;
  const float* x   = (const float*)d_in[0];
  const float* Wq  = (const float*)d_in[1];
  const float* bq  = (const float*)d_in[2];
  const float* Wk  = (const float*)d_in[3];
  const float* bk  = (const float*)d_in[4];
  const float* Wv  = (const float*)d_in[5];
  const float* bv  = (const float*)d_in[6];
  const float* Wo  = (const float*)d_in[7];
  const float* bo  = (const float*)d_in[8];
  const float* g1  = (const float*)d_in[9];
  const float* b1  = (const float*)d_in[10];
  const float* g2  = (const float*)d_in[11];
  const float* b2  = (const float*)d_in[12];
  const float* W1  = (const float*)d_in[13];
  const float* bf1 = (const float*)d_in[14];
  const float* W2  = (const float*)d_in[15];
  const float* bf2 = (const float*)d_in[16];

  u16* wsu  = (u16*)d_ws;
  u16* wq_t = wsu;                               // [3C][C] packed q,k,v
  u16* wo_t = wq_t + (size_t)3 * CH * CH;
  u16* w1_t = wo_t + (size_t)CH * CH;            // [FF][C]
  u16* w2_t = w1_t + (size_t)CH * FFD;           // [C][FF]
  u16* xn   = w2_t + (size_t)CH * FFD;           // [M][C]
  u16* qb   = xn + (size_t)MR * CH;              // q,k: [B*H][N][DH]; v: [B*H][DH][N]
  u16* zb   = qb + (size_t)3 * MR * CH;          // [B][N][C]
  u16* bres = zb + (size_t)MR * CH;              // [M][C] bf16 trunk
  u16* hb   = qb;                                // reuse region: [M][FF]
  float* bqkv = (float*)d_out;                   // packed bias (overwritten)

  dim3 blk(256);
  // prelude: weight transposes + bias pack + LN1, one launch (overlapped)
  k_prelude<<<6921 + 2048, blk, 0, stream>>>(Wq, Wk, Wv, Wo, W1, W2, wsu,
                                             bq, bk, bv, bqkv, x, g1, b1, xn);

  k_gemmk64<EPI_QKV><<<dim3(128, 18), blk, 0, stream>>>(
      xn, wq_t, bqkv, nullptr, qb, CH, 3 * CH);
  k_attn<<<768, dim3(512), 0, stream>>>(qb, qb + (size_t)MR * CH,
                                        qb + (size_t)2 * MR * CH, zb);
  k_gemmk64<EPI_BRES><<<dim3(128, 6), blk, 0, stream>>>(
      zb, wo_t, bo, x, bres, CH, CH);
  k_layernorm_b16src<<<2048, blk, 0, stream>>>(bres, g2, b2, xn);
  k_gemm128<EPI_RELU><<<dim3(64, 24), blk, 0, stream>>>(
      xn, w1_t, bf1, nullptr, hb, CH, FFD);
  k_gemmk64<EPI_OUT><<<dim3(128, 6), blk, 0, stream>>>(
      hb, w2_t, bf2, bres, (float*)d_out, FFD, CH);
}

// Round 21
// 223.252 us; speedup vs baseline: 1.0289x; 1.0289x over previous
//
#include <hip/hip_runtime.h>
#include <hip/hip_bf16.h>

// ViT encoder block: B=8, N=1024, C=768, H=12, DH=64, FF=3072, fp32 in/out,
// bf16 MFMA compute internally.
#define BDIM 8
#define SEQ  1024
#define CH   768
#define NHD  12
#define DHD  64
#define FFD  3072
#define MR   (BDIM*SEQ)   // 8192 token rows

typedef __attribute__((ext_vector_type(8))) short bf16x8;
typedef __attribute__((ext_vector_type(4))) float f32x4;
typedef unsigned int   u32;
typedef unsigned short u16;

#define QSCL 0.18033688f   // 0.125 * log2(e): Q pre-scale -> scores in log2

__device__ __forceinline__ u16 f2bfu(float x) {
  __hip_bfloat16 h = __float2bfloat16(x);
  return *reinterpret_cast<u16*>(&h);
}

__device__ __forceinline__ float bfu2f(u16 v) {
  u32 u = (u32)v << 16;
  return __uint_as_float(u);
}

__device__ __forceinline__ void glds16(const void* g, void* l) {
  __builtin_amdgcn_global_load_lds(
      (const __attribute__((address_space(1))) u32*)g,
      (__attribute__((address_space(3))) u32*)l, 16, 0, 0);
}

// ---------------------------------------------------------------- prelude
// ONE launch fusing three independent jobs:
//   blocks [0,6912):         weight transposes fp32 -> bf16 [N][K]
//   blocks [6912,6921):      bias pack bq|bk|bv -> bdst
//   blocks [6921,6921+2048): LN1  x -> xn (bf16)
__global__ __launch_bounds__(256) void k_prelude(
    const float* __restrict__ Wq, const float* __restrict__ Wk,
    const float* __restrict__ Wv, const float* __restrict__ Wo,
    const float* __restrict__ W1, const float* __restrict__ W2,
    u16* __restrict__ ws, const float* __restrict__ bq,
    const float* __restrict__ bk, const float* __restrict__ bv,
    float* __restrict__ bdst, const float* __restrict__ x,
    const float* __restrict__ g1, const float* __restrict__ b1,
    u16* __restrict__ xn) {
  __shared__ float tile[32][33];
  int b = blockIdx.x;
  if (b >= 6921) {
    // ---- LN1 (fp32 source) ----
    int row  = (b - 6921) * 4 + (threadIdx.x >> 6);
    int lane = threadIdx.x & 63;
    const float4* p4 = (const float4*)(x + (size_t)row * CH);
    float4 v[3];
    float s = 0.f, s2 = 0.f;
#pragma unroll
    for (int k = 0; k < 3; k++) {
      v[k] = p4[lane + k * 64];
      s  += v[k].x + v[k].y + v[k].z + v[k].w;
      s2 += v[k].x * v[k].x + v[k].y * v[k].y + v[k].z * v[k].z +
            v[k].w * v[k].w;
    }
#pragma unroll
    for (int m = 1; m < 64; m <<= 1) {
      s  += __shfl_xor(s,  m, 64);
      s2 += __shfl_xor(s2, m, 64);
    }
    float mean = s * (1.f / CH);
    float var  = s2 * (1.f / CH) - mean * mean;
    float rs   = rsqrtf(var + 1e-5f);
    u16* drow = xn + (size_t)row * CH;
#pragma unroll
    for (int k = 0; k < 3; k++) {
      int col = lane * 4 + k * 256;
      float4 gq = ((const float4*)g1)[lane + k * 64];
      float4 bq2 = ((const float4*)b1)[lane + k * 64];
      u32 lo = (u32)f2bfu((v[k].x - mean) * rs * gq.x + bq2.x) |
               ((u32)f2bfu((v[k].y - mean) * rs * gq.y + bq2.y) << 16);
      u32 hi = (u32)f2bfu((v[k].z - mean) * rs * gq.z + bq2.z) |
               ((u32)f2bfu((v[k].w - mean) * rs * gq.w + bq2.w) << 16);
      uint2 w; w.x = lo; w.y = hi;
      *(uint2*)(drow + col) = w;
    }
    return;
  }
  if (b >= 6912) {
    int i = (b - 6912) * 256 + threadIdx.x;
    if (i < 3 * CH)
      bdst[i] = i < CH ? bq[i] : (i < 2 * CH ? bk[i - CH] : bv[i - 2 * CH]);
    return;
  }
  int id, tb;
  if (b < 2304)      { id = b / 576; tb = b % 576; }
  else if (b < 4608) { id = 4;       tb = b - 2304; }
  else               { id = 5;       tb = b - 4608; }
  const float* src;
  u16* dst;
  int K, Nc;
  switch (id) {
    case 0: src = Wq; dst = ws;                      K = CH;  Nc = CH;  break;
    case 1: src = Wk; dst = ws + (size_t)CH*CH;      K = CH;  Nc = CH;  break;
    case 2: src = Wv; dst = ws + (size_t)2*CH*CH;    K = CH;  Nc = CH;  break;
    case 3: src = Wo; dst = ws + (size_t)3*CH*CH;    K = CH;  Nc = CH;  break;
    case 4: src = W1; dst = ws + (size_t)4*CH*CH;    K = CH;  Nc = FFD; break;
    default:src = W2; dst = ws + (size_t)4*CH*CH + (size_t)CH*FFD;
                                                     K = FFD; Nc = CH;  break;
  }
  int tilesx = Nc >> 5;
  int bx = (tb % tilesx) * 32;        // Nc dim
  int by = (tb / tilesx) * 32;        // K dim
  int tx = threadIdx.x & 31, ty = threadIdx.x >> 5;   // 32 x 8
#pragma unroll
  for (int j = 0; j < 32; j += 8)
    tile[ty + j][tx] = src[(size_t)(by + ty + j) * Nc + bx + tx];
  __syncthreads();
#pragma unroll
  for (int j = 0; j < 32; j += 8)
    dst[(size_t)(bx + ty + j) * K + by + tx] = f2bfu(tile[tx][ty + j]);
}

// ---------------------------------------------------------------- layernorm
// bf16 source (LN2: reads bres trunk stored bf16 -- halves its HBM fetch)
__global__ __launch_bounds__(256) void k_layernorm_b16src(
    const u16* __restrict__ src, const float* __restrict__ gamma,
    const float* __restrict__ beta, u16* __restrict__ dst) {
  int row  = blockIdx.x * 4 + (threadIdx.x >> 6);
  int lane = threadIdx.x & 63;
  const uint2* p2 = (const uint2*)(src + (size_t)row * CH);
  float v[3][4];
  float s = 0.f, s2 = 0.f;
#pragma unroll
  for (int k = 0; k < 3; k++) {
    uint2 w = p2[lane + k * 64];
    v[k][0] = bfu2f((u16)(w.x & 0xFFFF));
    v[k][1] = bfu2f((u16)(w.x >> 16));
    v[k][2] = bfu2f((u16)(w.y & 0xFFFF));
    v[k][3] = bfu2f((u16)(w.y >> 16));
#pragma unroll
    for (int j = 0; j < 4; j++) { s += v[k][j]; s2 += v[k][j] * v[k][j]; }
  }
#pragma unroll
  for (int m = 1; m < 64; m <<= 1) {
    s  += __shfl_xor(s,  m, 64);
    s2 += __shfl_xor(s2, m, 64);
  }
  float mean = s * (1.f / CH);
  float var  = s2 * (1.f / CH) - mean * mean;
  float rs   = rsqrtf(var + 1e-5f);
  u16* drow = dst + (size_t)row * CH;
#pragma unroll
  for (int k = 0; k < 3; k++) {
    int col = lane * 4 + k * 256;
    float4 gq = ((const float4*)gamma)[lane + k * 64];
    float4 bq = ((const float4*)beta )[lane + k * 64];
    u32 lo = (u32)f2bfu((v[k][0] - mean) * rs * gq.x + bq.x) |
             ((u32)f2bfu((v[k][1] - mean) * rs * gq.y + bq.y) << 16);
    u32 hi = (u32)f2bfu((v[k][2] - mean) * rs * gq.z + bq.z) |
             ((u32)f2bfu((v[k][3] - mean) * rs * gq.w + bq.w) << 16);
    uint2 w; w.x = lo; w.y = hi;
    *(uint2*)(drow + col) = w;
  }
}

enum { EPI_QKV = 0, EPI_BRES = 1, EPI_RELU = 2, EPI_OUT = 3 };

// ------------------------------------------------- shared epilogue (16x16)
// D row = (lane>>4)*4 + r, col = lane&15 (m89-verified mapping). row0 % 4 == 0.
// EPI_QKV: Q (sel==0) PRE-SCALED by QSCL (scores arrive in log2 domain).
// EPI_BRES: Wo out -- b = val + x(fp32), stored bf16 (trunk).
// EPI_OUT:  W2 out -- y = val + b(bf16), stored fp32 (final output).
template <int EPI>
__device__ __forceinline__ void gemm_epi(const f32x4& a, int row0, int col,
                                         float bval, const void* resid,
                                         void* outp, int Nmat) {
  if constexpr (EPI == EPI_QKV) {
    int sel = col / CH;                       // 128-col tile is within one sel
    int c = col - sel * CH;
    int h = c >> 6, d = c & 63;
    int bb = row0 >> 10, nn0 = row0 & (SEQ - 1);
    if (sel == 2) {
      // V stored TRANSPOSED per head: [B*H][DH][N]; 4 consecutive token rows
      union { uint2 u; u16 h4[4]; } pk;
#pragma unroll
      for (int r = 0; r < 4; r++) pk.h4[r] = f2bfu(a[r] + bval);
      *(uint2*)&((u16*)outp)[(size_t)2 * MR * CH +
                             (((size_t)(bb * NHD + h)) * DHD + d) * SEQ + nn0] =
          pk.u;
    } else {
      float scl = (sel == 0) ? QSCL : 1.f;    // uniform per col-tile
#pragma unroll
      for (int r = 0; r < 4; r++)
        ((u16*)outp)[(size_t)sel * MR * CH +
                     (((size_t)(bb * NHD + h)) * SEQ + nn0 + r) * DHD + d] =
            f2bfu((a[r] + bval) * scl);
    }
  } else if constexpr (EPI == EPI_BRES) {
#pragma unroll
    for (int r = 0; r < 4; r++) {
      size_t idx = (size_t)(row0 + r) * Nmat + col;
      ((u16*)outp)[idx] = f2bfu(a[r] + bval + ((const float*)resid)[idx]);
    }
  } else if constexpr (EPI == EPI_OUT) {
#pragma unroll
    for (int r = 0; r < 4; r++) {
      size_t idx = (size_t)(row0 + r) * Nmat + col;
      ((float*)outp)[idx] = a[r] + bval + bfu2f(((const u16*)resid)[idx]);
    }
  } else {  // RELU -> bf16 row-major
#pragma unroll
    for (int r = 0; r < 4; r++) {
      float val = a[r] + bval;
      ((u16*)outp)[(size_t)(row0 + r) * Nmat + col] =
          f2bfu(val > 0.f ? val : 0.f);
    }
  }
}

// ---------------------------------------------------------------- GEMM BK64
// Round-11/12 proven 2-phase: TM=64, BN=128, BK=64, conflicts 0 via row&7
// XOR swizzle (pre-swizzled source, dest linear, rule #21). LDS 48KB ->
// 3 blk/CU. Natural dispatch. QKV, Wo, W2 (grids 2304 / 768 / 768 blocks).
template <int EPI>
__global__ __launch_bounds__(256, 2) void k_gemmk64(
    const u16* __restrict__ A, const u16* __restrict__ Bt,
    const float* __restrict__ bias, const void* __restrict__ resid,
    void* __restrict__ outp, int K, int Nmat) {
  __shared__ u16 As[2][64 * 64];
  __shared__ u16 Bs[2][128 * 64];
  int tid = threadIdx.x;
  int bm = blockIdx.x, bn = blockIdx.y;
  int lane = tid & 63, wid = tid >> 6;
  int wr = (wid >> 1) * 32, wc = (wid & 1) * 64;
  int lrow = lane & 15, g = lane >> 4;

  const u16* Abase = A + (size_t)(bm * 64) * K;
  const u16* Bbase = Bt + (size_t)(bn * 128) * K;

  auto stage = [&](int buf, int k0) {
#pragma unroll
    for (int r = 0; r < 2; r++) {               // A: 512 units
      int u = tid + r * 256;
      int row = u >> 3, slot = u & 7;
      glds16(Abase + (size_t)row * K + k0 + ((slot ^ (row & 7)) << 3),
             &As[buf][u * 8]);
    }
#pragma unroll
    for (int r = 0; r < 4; r++) {               // B: 1024 units
      int u = tid + r * 256;
      int row = u >> 3, slot = u & 7;
      glds16(Bbase + (size_t)row * K + k0 + ((slot ^ (row & 7)) << 3),
             &Bs[buf][u * 8]);
    }
  };

  int sx = lrow & 7;
  int x0 = (g ^ sx) * 8;            // ks=0: logical slot g
  int x1 = ((4 + g) ^ sx) * 8;      // ks=1: logical slot 4+g

  f32x4 acc[2][4];
#pragma unroll
  for (int m = 0; m < 2; m++)
#pragma unroll
    for (int n = 0; n < 4; n++) acc[m][n] = {0.f, 0.f, 0.f, 0.f};

  int nk = K >> 6;
  stage(0, 0);
  for (int kt = 0; kt < nk; ++kt) {
    int buf = kt & 1;
    __syncthreads();
    if (kt + 1 < nk) stage(buf ^ 1, (kt + 1) << 6);
#pragma unroll
    for (int ks = 0; ks < 2; ks++) {
      int xs = ks ? x1 : x0;
      bf16x8 af[2], bfr[4];
#pragma unroll
      for (int m = 0; m < 2; m++)
        af[m] = *(const bf16x8*)&As[buf][(wr + m * 16 + lrow) * 64 + xs];
#pragma unroll
      for (int n = 0; n < 4; n++)
        bfr[n] = *(const bf16x8*)&Bs[buf][(wc + n * 16 + lrow) * 64 + xs];
      __builtin_amdgcn_s_setprio(1);
#pragma unroll
      for (int m = 0; m < 2; m++)
#pragma unroll
        for (int n = 0; n < 4; n++)
          acc[m][n] = __builtin_amdgcn_mfma_f32_16x16x32_bf16(
              af[m], bfr[n], acc[m][n], 0, 0, 0);
      __builtin_amdgcn_s_setprio(0);
    }
  }

#pragma unroll
  for (int m = 0; m < 2; m++) {
    int row0 = bm * 64 + wr + m * 16 + g * 4;
#pragma unroll
    for (int n = 0; n < 4; n++) {
      int col = bn * 128 + wc + n * 16 + lrow;
      gemm_epi<EPI>(acc[m][n], row0, col, bias[col], resid, outp, Nmat);
    }
  }
}

// ---------------------------------------------------------------- GEMM 128x64
// TM=128, BN=128, BK=64: 2x MFMA per barrier at MFMA:ds ratio 2.0. LDS 64KB
// -> 2 blk/CU. Round-16: wins for W1 (grid 1536 = 3 full dispatch rounds,
// 48 K-tiles); loses for QKV (tail). W1 ONLY.
template <int EPI>
__global__ __launch_bounds__(256, 2) void k_gemm128(
    const u16* __restrict__ A, const u16* __restrict__ Bt,
    const float* __restrict__ bias, const void* __restrict__ resid,
    void* __restrict__ outp, int K, int Nmat) {
  __shared__ u16 As[2][128 * 64];
  __shared__ u16 Bs[2][128 * 64];
  int tid = threadIdx.x;
  int bm = blockIdx.x, bn = blockIdx.y;
  int lane = tid & 63, wid = tid >> 6;
  int wr = (wid >> 1) * 64, wc = (wid & 1) * 64;
  int lrow = lane & 15, g = lane >> 4;

  const u16* Abase = A + (size_t)(bm * 128) * K;
  const u16* Bbase = Bt + (size_t)(bn * 128) * K;

  auto stage = [&](int buf, int k0) {
#pragma unroll
    for (int r = 0; r < 4; r++) {               // A: 1024 units
      int u = tid + r * 256;
      int row = u >> 3, slot = u & 7;
      glds16(Abase + (size_t)row * K + k0 + ((slot ^ (row & 7)) << 3),
             &As[buf][u * 8]);
    }
#pragma unroll
    for (int r = 0; r < 4; r++) {               // B: 1024 units
      int u = tid + r * 256;
      int row = u >> 3, slot = u & 7;
      glds16(Bbase + (size_t)row * K + k0 + ((slot ^ (row & 7)) << 3),
             &Bs[buf][u * 8]);
    }
  };

  int sx = lrow & 7;
  int x0 = (g ^ sx) * 8;            // ks=0: logical slot g
  int x1 = ((4 + g) ^ sx) * 8;      // ks=1: logical slot 4+g

  f32x4 acc[4][4];
#pragma unroll
  for (int m = 0; m < 4; m++)
#pragma unroll
    for (int n = 0; n < 4; n++) acc[m][n] = {0.f, 0.f, 0.f, 0.f};

  int nk = K >> 6;
  stage(0, 0);
  for (int kt = 0; kt < nk; ++kt) {
    int buf = kt & 1;
    __syncthreads();
    if (kt + 1 < nk) stage(buf ^ 1, (kt + 1) << 6);
#pragma unroll
    for (int ks = 0; ks < 2; ks++) {
      int xs = ks ? x1 : x0;
      bf16x8 af[4], bfr[4];
#pragma unroll
      for (int m = 0; m < 4; m++)
        af[m] = *(const bf16x8*)&As[buf][(wr + m * 16 + lrow) * 64 + xs];
#pragma unroll
      for (int n = 0; n < 4; n++)
        bfr[n] = *(const bf16x8*)&Bs[buf][(wc + n * 16 + lrow) * 64 + xs];
      __builtin_amdgcn_s_setprio(1);
#pragma unroll
      for (int m = 0; m < 4; m++)
#pragma unroll
        for (int n = 0; n < 4; n++)
          acc[m][n] = __builtin_amdgcn_mfma_f32_16x16x32_bf16(
              af[m], bfr[n], acc[m][n], 0, 0, 0);
      __builtin_amdgcn_s_setprio(0);
    }
  }

#pragma unroll
  for (int m = 0; m < 4; m++) {
    int row0 = bm * 128 + wr + m * 16 + g * 4;
#pragma unroll
    for (int n = 0; n < 4; n++) {
      int col = bn * 128 + wc + n * 16 + lrow;
      gemm_epi<EPI>(acc[m][n], row0, col, bias[col], resid, outp, Nmat);
    }
  }
}

// ---------------------------------------------------------------- attention
// (round-19 measured-best version) flash-style, SWAPPED QK^T, glds-staged
// swizzled K / V^T tiles, defer-max, 8 waves x 16 q-rows, XCD swizzle, Q
// pre-scaled to log2 domain, raw v_exp_f32, MFMA row-sum denominator, max3
// tree, Psu LDS repack table. (Round-20's __shfl repack REGRESSED: variable-
// lane shfl = ds_bpermute = LDS-pipe op; conflicts doubled, occupancy flat.)
__global__ __launch_bounds__(512, 4) void k_attn(
    const u16* __restrict__ Q, const u16* __restrict__ Kk,
    const u16* __restrict__ Vt, u16* __restrict__ Z) {
  __shared__ u16 Ks[2][64 * 64];
  __shared__ u16 Vs[2][64 * 64];     // V^T tile: [d][kv]
  __shared__ u32 Psu[8][64 * 9];     // per-wave P repack: [lane][2n+hi]
  int tid = threadIdx.x, lane = tid & 63, wid = tid >> 6;
  int lrow = lane & 15, g = lane >> 4;
  int id  = blockIdx.x;
  int nid = (id & 7) * 96 + (id >> 3);
  int bh = nid >> 3;
  int qtile = (nid & 7) * 128;
  size_t base = (size_t)bh * SEQ * DHD;
  int bb = bh / NHD, hh = bh % NHD;
  int qrow0 = qtile + wid * 16;

  bf16x8 qf[2];
#pragma unroll
  for (int ks = 0; ks < 2; ks++)
    qf[ks] = *(const bf16x8*)(Q + base + (size_t)(qrow0 + lrow) * DHD +
                              ks * 32 + g * 8);

  bf16x8 vone;
#pragma unroll
  for (int j = 0; j < 8; j++) vone[j] = (short)0x3F80;   // bf16 1.0

  f32x4 accO[4];
  f32x4 accS = {0.f, 0.f, 0.f, 0.f};   // denominator, same layout as accO
  float mrun = -1e30f;                  // log2 units
#pragma unroll
  for (int n = 0; n < 4; n++) accO[n] = {0.f, 0.f, 0.f, 0.f};

  int srow = tid >> 3;
  int swz  = (((tid & 7) * 16) ^ ((srow & 7) << 4)) >> 1;   // u16 units
  const u16* kg0 = Kk + base + (size_t)srow * DHD + swz;
  const u16* vg0 = Vt + base + (size_t)srow * SEQ + swz;

  auto stageKV = [&](int buf, int t) {
    glds16(kg0 + (size_t)t * 64 * DHD, &Ks[buf][tid * 8]);
    glds16(vg0 + t * 64,               &Vs[buf][tid * 8]);
  };

  int rc0 = ((g * 16)      ^ ((lrow & 7) << 4)) >> 1;
  int rc1 = ((64 + g * 16) ^ ((lrow & 7) << 4)) >> 1;

  auto mx3 = [](float a, float b, float c) { return fmaxf(fmaxf(a, b), c); };

  stageKV(0, 0);
  for (int t = 0; t < 16; ++t) {
    int buf = t & 1;
    __syncthreads();
    if (t + 1 < 16) stageKV(buf ^ 1, t + 1);

    f32x4 sacc[4];
    __builtin_amdgcn_s_setprio(1);
#pragma unroll
    for (int n = 0; n < 4; n++) {
      bf16x8 kf0 = *(const bf16x8*)&Ks[buf][(n * 16 + lrow) * 64 + rc0];
      bf16x8 kf1 = *(const bf16x8*)&Ks[buf][(n * 16 + lrow) * 64 + rc1];
      sacc[n] = {0.f, 0.f, 0.f, 0.f};
      sacc[n] = __builtin_amdgcn_mfma_f32_16x16x32_bf16(kf0, qf[0], sacc[n], 0, 0, 0);
      sacc[n] = __builtin_amdgcn_mfma_f32_16x16x32_bf16(kf1, qf[1], sacc[n], 0, 0, 0);
    }
    __builtin_amdgcn_s_setprio(0);

    float a0 = mx3(sacc[0][0], sacc[0][1], sacc[0][2]);
    float a1 = mx3(sacc[0][3], sacc[1][0], sacc[1][1]);
    float a2 = mx3(sacc[1][2], sacc[1][3], sacc[2][0]);
    float a3 = mx3(sacc[2][1], sacc[2][2], sacc[2][3]);
    float a4 = mx3(sacc[3][0], sacc[3][1], sacc[3][2]);
    float mx = fmaxf(mx3(a0, a1, a2), mx3(a3, a4, sacc[3][3]));
    mx = fmaxf(mx, __shfl_xor(mx, 16, 64));
    mx = fmaxf(mx, __shfl_xor(mx, 32, 64));

    if (__all(mx <= mrun + 11.54f)) {   // 8 nats in bits
#pragma unroll
      for (int n = 0; n < 4; n++)
#pragma unroll
        for (int r = 0; r < 4; r++)
          sacc[n][r] = __builtin_amdgcn_exp2f(sacc[n][r] - mrun);
    } else {
      float mnew = fmaxf(mrun, mx);
      float alpha = __builtin_amdgcn_exp2f(mrun - mnew);
#pragma unroll
      for (int n = 0; n < 4; n++)
#pragma unroll
        for (int r = 0; r < 4; r++)
          sacc[n][r] = __builtin_amdgcn_exp2f(sacc[n][r] - mnew);
      mrun = mnew;
#pragma unroll
      for (int r = 0; r < 4; r++) {
        float ar = __shfl(alpha, (lane & 48) | (g * 4 + r), 64);
        accS[r] *= ar;
#pragma unroll
        for (int n = 0; n < 4; n++) accO[n][r] *= ar;
      }
    }

#pragma unroll
    for (int n = 0; n < 4; n++) {
      u32 lo = (u32)f2bfu(sacc[n][0]) | ((u32)f2bfu(sacc[n][1]) << 16);
      u32 hi = (u32)f2bfu(sacc[n][2]) | ((u32)f2bfu(sacc[n][3]) << 16);
      Psu[wid][lane * 9 + 2 * n]     = lo;
      Psu[wid][lane * 9 + 2 * n + 1] = hi;
    }

    int laneA = lrow + ((g & 1) << 5);
    int laneB = laneA + 16;
    int nsel = g >> 1;
    __builtin_amdgcn_s_setprio(1);
#pragma unroll
    for (int ks = 0; ks < 2; ks++) {
      int nks = 2 * ks + nsel;
      union { bf16x8 v; u32 w[4]; } pk;
      pk.w[0] = Psu[wid][laneA * 9 + 2 * nks];
      pk.w[1] = Psu[wid][laneA * 9 + 2 * nks + 1];
      pk.w[2] = Psu[wid][laneB * 9 + 2 * nks];
      pk.w[3] = Psu[wid][laneB * 9 + 2 * nks + 1];
      int rc = ks ? rc1 : rc0;
#pragma unroll
      for (int n = 0; n < 4; n++) {
        bf16x8 vf = *(const bf16x8*)&Vs[buf][(n * 16 + lrow) * 64 + rc];
        accO[n] = __builtin_amdgcn_mfma_f32_16x16x32_bf16(pk.v, vf,
                                                          accO[n], 0, 0, 0);
      }
      accS = __builtin_amdgcn_mfma_f32_16x16x32_bf16(pk.v, vone, accS, 0, 0, 0);
    }
    __builtin_amdgcn_s_setprio(0);
  }

#pragma unroll
  for (int r = 0; r < 4; r++) {
    float inv = 1.f / accS[r];
    int qrow = qrow0 + g * 4 + r;
#pragma unroll
    for (int n = 0; n < 4; n++) {
      int d = n * 16 + lrow;
      Z[((size_t)(bb * SEQ + qrow)) * CH + hh * DHD + d] =
          f2bfu(accO[n][r] * inv);
    }
  }
}

// ---------------------------------------------------------------- launch
extern "C" void kernel_launch(void* const* d_in, const int* in_sizes, int n_in,
                              void* d_out, int out_size, void* d_ws,
                              size_t ws_size, hipStream_t stream) {
  (void)in_sizes; (void)n_in; (void)out_size; (void)ws_size;
  const float* x   = (const float*)d_in[0];
  const float* Wq  = (const float*)d_in[1];
  const float* bq  = (const float*)d_in[2];
  const float* Wk  = (const float*)d_in[3];
  const float* bk  = (const float*)d_in[4];
  const float* Wv  = (const float*)d_in[5];
  const float* bv  = (const float*)d_in[6];
  const float* Wo  = (const float*)d_in[7];
  const float* bo  = (const float*)d_in[8];
  const float* g1  = (const float*)d_in[9];
  const float* b1  = (const float*)d_in[10];
  const float* g2  = (const float*)d_in[11];
  const float* b2  = (const float*)d_in[12];
  const float* W1  = (const float*)d_in[13];
  const float* bf1 = (const float*)d_in[14];
  const float* W2  = (const float*)d_in[15];
  const float* bf2 = (const float*)d_in[16];

  u16* wsu  = (u16*)d_ws;
  u16* wq_t = wsu;                               // [3C][C] packed q,k,v
  u16* wo_t = wq_t + (size_t)3 * CH * CH;
  u16* w1_t = wo_t + (size_t)CH * CH;            // [FF][C]
  u16* w2_t = w1_t + (size_t)CH * FFD;           // [C][FF]
  u16* xn   = w2_t + (size_t)CH * FFD;           // [M][C]
  u16* qb   = xn + (size_t)MR * CH;              // q,k: [B*H][N][DH]; v: [B*H][DH][N]
  u16* zb   = qb + (size_t)3 * MR * CH;          // [B][N][C]
  u16* bres = zb + (size_t)MR * CH;              // [M][C] bf16 trunk
  u16* hb   = qb;                                // reuse region: [M][FF]
  float* bqkv = (float*)d_out;                   // packed bias (overwritten)

  dim3 blk(256);
  // prelude: weight transposes + bias pack + LN1, one launch (overlapped)
  k_prelude<<<6921 + 2048, blk, 0, stream>>>(Wq, Wk, Wv, Wo, W1, W2, wsu,
                                             bq, bk, bv, bqkv, x, g1, b1, xn);

  k_gemmk64<EPI_QKV><<<dim3(128, 18), blk, 0, stream>>>(
      xn, wq_t, bqkv, nullptr, qb, CH, 3 * CH);
  k_attn<<<768, dim3(512), 0, stream>>>(qb, qb + (size_t)MR * CH,
                                        qb + (size_t)2 * MR * CH, zb);
  k_gemmk64<EPI_BRES><<<dim3(128, 6), blk, 0, stream>>>(
      zb, wo_t, bo, x, bres, CH, CH);
  k_layernorm_b16src<<<2048, blk, 0, stream>>>(bres, g2, b2, xn);
  k_gemm128<EPI_RELU><<<dim3(64, 24), blk, 0, stream>>>(
      xn, w1_t, bf1, nullptr, hb, CH, FFD);
  k_gemmk64<EPI_OUT><<<dim3(128, 6), blk, 0, stream>>>(
      hb, w2_t, bf2, bres, (float*)d_out, FFD, CH);
}